// Round 8
// baseline (246.849 us; speedup 1.0000x reference)
//
#include <hip/hip_runtime.h>
#include <stdint.h>

// ---------------------------------------------------------------------------
// MultiScaleGRU fused pipeline (MI355X / gfx950)
//
//   gi = (A @ C) @ w_ih^T + b_ih      A: [16384,4096] fp32 (attention_weights)
//   gh = h @ w_hh^T + b_hh            h: repeat(C[:16], 4)  -> [64,256]
//   r,z = sigmoid(gi_rz + gh_rz); n = tanh(gi_n + r*gh_n)
//   h_new = (1-z)*n + z*h ; out[o,b,:] = mean_j h_new[b, 4o+j, :]
//
// Precision plan (passing: absmax 0.0195 vs 7.5e-2):
//  - A centered bf16(a-0.5) + exact 0.5*colsum(C) correction.
//  - C split hi+lo bf16; X carried hi+lo bf16; W split hi+lo bf16
//    (GI = Xh@Wh + Xl@Wh + Xh@Wl). Accumulation order unchanged.
//
// Perf (R8): R7 counters showed stage1 L3-bound on Ct re-reads (A's 256MB
// stream evicts the 4MB Ct panel from every XCD L2; B then costs ~2600cy/iter
// from L3 vs compute ~1150cy, all stalls exposed at 1 block/CU). Fix: A is
// zero-reuse -> nontemporal loads (nt bit, no L2 pollution) so Ct stays
// L2-resident; stage2 X staging uses NT CPol (aux=2) likewise to protect W.
// ---------------------------------------------------------------------------

typedef short short8 __attribute__((ext_vector_type(8)));
typedef float f32x4 __attribute__((ext_vector_type(4)));

// workspace layout (bytes)
#define WS_CTH  0u          // Ct hi : bf16 [256][4096] swz   (2 MB)
#define WS_CTL  2097152u    // Ct lo : bf16 [256][4096] swz   (2 MB)
#define WS_WPH  4194304u    // Wp hi : bf16 [768][256]  swz   (384 KB)
#define WS_WPL  4587520u    // Wp lo : bf16 [768][256]  swz   (384 KB)
#define WS_GH   4980736u    // GH    : f32  [64][768]         (192 KB)
#define WS_CSP  5177344u    // csum partials: f32 [16][256]   (16 KB)
#define WS_CS   5193728u    // csum  : f32 [256]              (1 KB)
#define WS_XHI  5194752u    // Xhi   : bf16 [16384][256] swz  (8 MB)
#define WS_XLO  13583360u   // Xlo   : bf16 [16384][256] swz  (8 MB)
// total 21,971,968 bytes

static __device__ __forceinline__ unsigned short f2bf(float x) {
  // fp32 -> bf16 round-to-nearest-even (explicit; avoids truncation bias)
  unsigned u = __builtin_bit_cast(unsigned, x);
  u += 0x7FFFu + ((u >> 16) & 1u);
  return (unsigned short)(u >> 16);
}
static __device__ __forceinline__ float bf2f(unsigned short h) {
  unsigned u = ((unsigned)h) << 16;
  return __builtin_bit_cast(float, u);
}
static __device__ __forceinline__ void gload16(const void* g, void* lds) {
  // async global->LDS, 16B/lane; LDS dest = wave-uniform base + lane*16
  __builtin_amdgcn_global_load_lds(
      (const __attribute__((address_space(1))) unsigned int*)g,
      (__attribute__((address_space(3))) unsigned int*)lds, 16, 0, 0);
}
static __device__ __forceinline__ void gload16nt(const void* g, void* lds) {
  // NT CPol (gfx940+ encoding: SC0=1, NT=2, SC1=16) -> streaming, spare L2
  __builtin_amdgcn_global_load_lds(
      (const __attribute__((address_space(1))) unsigned int*)g,
      (__attribute__((address_space(3))) unsigned int*)lds, 16, 0, 2);
}
static __device__ __forceinline__ float sigmf(float x) {
  float e = __expf(-fabsf(x));
  float p = 1.f / (1.f + e);
  return x >= 0.f ? p : 1.f - p;
}
static __device__ __forceinline__ float tanhf2(float x) {
  float e = __expf(-2.f * fabsf(x));
  float t = 1.f - 2.f * e / (1.f + e);
  return x >= 0.f ? t : -t;
}

// ---------------------------------------------------------------------------
// prep 1: C[4096][256] f32 -> Ct_hi/Ct_lo [256(h)][4096(f)] bf16, swizzled
__global__ void __launch_bounds__(256) k_transC(const float* __restrict__ C,
                                                unsigned short* __restrict__ Cth,
                                                unsigned short* __restrict__ Ctl) {
  __shared__ float sT[64][65];
  const int f0 = blockIdx.x * 64, h0 = blockIdx.y * 64;
  const int t = threadIdx.x;
#pragma unroll
  for (int i = 0; i < 4; ++i) {
    int fl = t + 256 * i;
    int r = fl >> 4, c4 = fl & 15;
    float4 v = *(const float4*)(C + (size_t)(f0 + r) * 256 + h0 + c4 * 4);
    sT[r][c4 * 4 + 0] = v.x; sT[r][c4 * 4 + 1] = v.y;
    sT[r][c4 * 4 + 2] = v.z; sT[r][c4 * 4 + 3] = v.w;
  }
  __syncthreads();
#pragma unroll
  for (int i = 0; i < 2; ++i) {
    int q = t + 256 * i;         // 512 chunks of 8 bf16
    int hr = q >> 3, j = q & 7;  // out row (h), f-chunk within 64
    int h = h0 + hr;
    union { short8 v; unsigned short u[8]; } ph, pl;
#pragma unroll
    for (int u = 0; u < 8; ++u) {
      float v = sT[j * 8 + u][hr];
      unsigned short hi = f2bf(v);
      ph.u[u] = hi;
      pl.u[u] = f2bf(v - bf2f(hi));
    }
    size_t off = (size_t)h * 8192 + (size_t)f0 * 2 + (size_t)((j ^ (h & 7)) << 4);
    *(short8*)((char*)Cth + off) = ph.v;
    *(short8*)((char*)Ctl + off) = pl.v;
  }
}

// prep 1b: colsum partials (deterministic 2-step tree, no fp32 atomics)
__global__ void __launch_bounds__(256) k_csum(const float* __restrict__ C,
                                              float* __restrict__ part) {
  const int b = blockIdx.x, t = threadIdx.x;
  float s = 0.f;
  for (int k = 0; k < 256; ++k) s += C[(size_t)(b * 256 + k) * 256 + t];
  part[b * 256 + t] = s;
}
__global__ void __launch_bounds__(256) k_csum2(const float* __restrict__ part,
                                               float* __restrict__ csum) {
  const int t = threadIdx.x;
  float s = 0.f;
#pragma unroll
  for (int b = 0; b < 16; ++b) s += part[b * 256 + t];
  csum[t] = 0.5f * s;  // correction for A centered at 0.5
}

// prep 2: w_ih[768][256] f32 -> Wp_hi/Wp_lo [n'=3h+g][256] bf16, swizzled
__global__ void __launch_bounds__(256) k_prepWp(const float* __restrict__ w_ih,
                                                unsigned short* __restrict__ Wph,
                                                unsigned short* __restrict__ Wpl) {
  int q = blockIdx.x * 256 + threadIdx.x;  // 24576 chunks
  int row = q >> 5, c = q & 31;
  int seg = c >> 3, j = c & 7;
  int srow = (row % 3) * 256 + row / 3;    // gate-interleave permutation
  const float* src = w_ih + (size_t)srow * 256 + c * 8;
  union { short8 v; unsigned short u[8]; } ph, pl;
#pragma unroll
  for (int u = 0; u < 8; ++u) {
    float v = src[u];
    unsigned short hi = f2bf(v);
    ph.u[u] = hi;
    pl.u[u] = f2bf(v - bf2f(hi));
  }
  size_t off = (size_t)row * 512 + seg * 128 + ((j ^ (row & 7)) << 4);
  *(short8*)((char*)Wph + off) = ph.v;
  *(short8*)((char*)Wpl + off) = pl.v;
}

// prep 3: GH[64][768] = h @ w_hh^T + b_hh   (exact fp32)
__global__ void __launch_bounds__(256) k_gh(const float* __restrict__ centers,
                                            const float* __restrict__ w_hh,
                                            const float* __restrict__ b_hh,
                                            float* __restrict__ GH) {
  __shared__ __align__(16) float sH[256];
  const int s = blockIdx.x, t = threadIdx.x;
  sH[t] = centers[(size_t)(s >> 2) * 256 + t];
  __syncthreads();
#pragma unroll
  for (int e = 0; e < 3; ++e) {
    int n = e * 256 + t;
    float accv = b_hh[n];
    const float4* w = (const float4*)(w_hh + (size_t)n * 256);
#pragma unroll 8
    for (int k = 0; k < 64; ++k) {
      float4 v = w[k];
      float4 hh = *(const float4*)&sH[k * 4];
      accv += v.x * hh.x + v.y * hh.y + v.z * hh.z + v.w * hh.w;
    }
    GH[(size_t)s * 768 + n] = accv;
  }
}

// ---------------------------------------------------------------------------
// stage 1: X = (A-0.5) @ (C_hi + C_lo) + 0.5*colsum(C).
// BM=64, BN=256(full H), BK=64. grid 256 (1 block/CU), 256 thr, 4 waves 2Mx2N.
// A loaded NONTEMPORAL (zero reuse; keeps Ct L2-resident). 2-phase pipeline:
// B double-buffered via global_load_lds, next tile issued before the compute
// barrier (raw s_barrier + lgkmcnt fence); trailing __syncthreads() is the
// single vmcnt(0) drain per tile.
__global__ void __launch_bounds__(256) k_stage1(const float* __restrict__ A,
                                                const unsigned short* __restrict__ Cth,
                                                const unsigned short* __restrict__ Ctl,
                                                const float* __restrict__ csum,
                                                unsigned short* __restrict__ Xhi,
                                                unsigned short* __restrict__ Xlo) {
  __shared__ __align__(16) short sA[64 * 64];       //  8 KB
  __shared__ __align__(16) short sBh[2][256 * 64];  // 64 KB (dbuf)
  __shared__ __align__(16) short sBl[2][256 * 64];  // 64 KB (dbuf)
  const int t = threadIdx.x;
  const int wid = t >> 6, l = t & 63;
  const int lr = l & 15, lk = l >> 4;
  const int wm = wid >> 1, wn = wid & 1;
  const int m0 = blockIdx.x * 64;

  f32x4 acc[2][8];
#pragma unroll
  for (int i = 0; i < 2; ++i)
#pragma unroll
    for (int j = 0; j < 8; ++j) acc[i][j] = (f32x4){0.f, 0.f, 0.f, 0.f};

  // A staging: thread t -> row ar (0..63), 16-float chunk aq (0..3)
  const int ar = t >> 2, aq = t & 3;
  const float* aptr = A + (size_t)(m0 + ar) * 4096 + aq * 16;
  const int sw0 = ar * 128 + (((2 * aq) ^ (ar & 7)) << 4);
  const int sw1 = ar * 128 + (((2 * aq + 1) ^ (ar & 7)) << 4);

  // B staging: flat = t + 256*i -> row br+32i, chunk bj; dest = linear chunk
  const int br = t >> 3, bj = t & 7;

  // prologue: A(0) regs (NT) + B(0) -> buf 0
  f32x4 a0 = __builtin_nontemporal_load((const f32x4*)(aptr));
  f32x4 a1 = __builtin_nontemporal_load((const f32x4*)(aptr + 4));
  f32x4 a2 = __builtin_nontemporal_load((const f32x4*)(aptr + 8));
  f32x4 a3 = __builtin_nontemporal_load((const f32x4*)(aptr + 12));
#pragma unroll
  for (int i = 0; i < 8; ++i) {
    size_t so = (size_t)(br + 32 * i) * 4096 + bj * 8;
    int db = (wid * 64 + 256 * i) * 16;
    gload16(Cth + so, (char*)&sBh[0][0] + db);
    gload16(Ctl + so, (char*)&sBl[0][0] + db);
  }
  asm volatile("s_waitcnt vmcnt(0)" ::: "memory");

#pragma unroll 2
  for (int kk = 0; kk < 64; ++kk) {
    const int cur = kk & 1;
    // ds_write A(kk) (centered, RNE) -> sA  [prev reads fenced by last barrier]
    {
      union { short8 v; unsigned short u[8]; } p0, p1;
      p0.u[0] = f2bf(a0.x - 0.5f); p0.u[1] = f2bf(a0.y - 0.5f);
      p0.u[2] = f2bf(a0.z - 0.5f); p0.u[3] = f2bf(a0.w - 0.5f);
      p0.u[4] = f2bf(a1.x - 0.5f); p0.u[5] = f2bf(a1.y - 0.5f);
      p0.u[6] = f2bf(a1.z - 0.5f); p0.u[7] = f2bf(a1.w - 0.5f);
      p1.u[0] = f2bf(a2.x - 0.5f); p1.u[1] = f2bf(a2.y - 0.5f);
      p1.u[2] = f2bf(a2.z - 0.5f); p1.u[3] = f2bf(a2.w - 0.5f);
      p1.u[4] = f2bf(a3.x - 0.5f); p1.u[5] = f2bf(a3.y - 0.5f);
      p1.u[6] = f2bf(a3.z - 0.5f); p1.u[7] = f2bf(a3.w - 0.5f);
      *(short8*)((char*)sA + sw0) = p0.v;
      *(short8*)((char*)sA + sw1) = p1.v;
    }
    // issue next tile: A(kk+1) -> regs (NT), B(kk+1) -> buf[cur^1]
    f32x4 n0, n1, n2, n3;
    if (kk < 63) {
      const float* ap = aptr + (kk + 1) * 64;
      n0 = __builtin_nontemporal_load((const f32x4*)(ap));
      n1 = __builtin_nontemporal_load((const f32x4*)(ap + 4));
      n2 = __builtin_nontemporal_load((const f32x4*)(ap + 8));
      n3 = __builtin_nontemporal_load((const f32x4*)(ap + 12));
#pragma unroll
      for (int i = 0; i < 8; ++i) {
        size_t so = (size_t)(br + 32 * i) * 4096 + (size_t)(kk + 1) * 64 + bj * 8;
        int db = (wid * 64 + 256 * i) * 16;
        gload16(Cth + so, (char*)&sBh[cur ^ 1][0] + db);
        gload16(Ctl + so, (char*)&sBl[cur ^ 1][0] + db);
      }
    }
    // raw barrier: A(kk) visible; B(kk) visible (drained by prev iter's
    // __syncthreads). Does NOT drain the in-flight B(kk+1) stage.
    asm volatile("s_waitcnt lgkmcnt(0)" ::: "memory");
    __builtin_amdgcn_s_barrier();
    asm volatile("" ::: "memory");

    const char* pA = (const char*)sA;
    const char* pBh = (const char*)&sBh[cur][0];
    const char* pBl = (const char*)&sBl[cur][0];
#pragma unroll
    for (int kc = 0; kc < 2; ++kc) {
      const int q = kc * 4 + lk;
      short8 af[2];
#pragma unroll
      for (int mi = 0; mi < 2; ++mi) {
        int rl = wm * 32 + mi * 16 + lr;
        af[mi] = *(const short8*)(pA + rl * 128 + ((q ^ (rl & 7)) << 4));
      }
#pragma unroll
      for (int ni = 0; ni < 8; ++ni) {
        int rb = wn * 128 + ni * 16 + lr;
        int so = rb * 128 + ((q ^ (rb & 7)) << 4);
        short8 bh = *(const short8*)(pBh + so);
        short8 bl = *(const short8*)(pBl + so);
#pragma unroll
        for (int mi = 0; mi < 2; ++mi) {
          acc[mi][ni] = __builtin_amdgcn_mfma_f32_16x16x32_bf16(af[mi], bh, acc[mi][ni], 0, 0, 0);
          acc[mi][ni] = __builtin_amdgcn_mfma_f32_16x16x32_bf16(af[mi], bl, acc[mi][ni], 0, 0, 0);
        }
      }
    }
    // drain next-tile stage (vmcnt(0)) + cross-wave reads-done fence
    __syncthreads();
    if (kk < 63) { a0 = n0; a1 = n1; a2 = n2; a3 = n3; }
  }

  // epilogue: add centering correction, X -> hi/lo bf16, pre-swizzled storage
  // (normal stores: L3 absorbs and serves stage2 - WRITE_SIZE shows 16/32 MB)
  float cs[8];
#pragma unroll
  for (int ni = 0; ni < 8; ++ni) cs[ni] = csum[wn * 128 + ni * 16 + lr];
#pragma unroll
  for (int mi = 0; mi < 2; ++mi)
#pragma unroll
    for (int ni = 0; ni < 8; ++ni)
#pragma unroll
      for (int p = 0; p < 4; ++p) {
        int m = m0 + wm * 32 + mi * 16 + lk * 4 + p;  // C/D: row=(lane>>4)*4+reg
        int col = wn * 128 + ni * 16 + lr;            //      col=lane&15
        float x = acc[mi][ni][p] + cs[ni];
        unsigned short hi = f2bf(x);
        unsigned short lo = f2bf(x - bf2f(hi));
        size_t off = (size_t)m * 512 + ((col >> 6) << 7) +
                     ((((col >> 3) & 7) ^ (m & 7)) << 4) + ((col & 7) << 1);
        *(unsigned short*)((char*)Xhi + off) = hi;
        *(unsigned short*)((char*)Xlo + off) = lo;
      }
}

// ---------------------------------------------------------------------------
// stage 2: GI = Xhi@Whi + Xlo@Whi + Xhi@Wlo + fused GRU + level-mean.
// grid 256 (block = batch b), 256 thr, 4 waves 2Mx2N. X panel (hi+lo, 64 KB)
// resident in LDS, staged with NT CPol (streaming; keeps W L2-resident);
// W tiles (96x256, 48 KB) staged once per (ntile, hi/lo). sC aliases sW.
__global__ void __launch_bounds__(256) k_stage2(const unsigned short* __restrict__ Xhi,
                                                const unsigned short* __restrict__ Xlo,
                                                const unsigned short* __restrict__ Wph,
                                                const unsigned short* __restrict__ Wpl,
                                                const float* __restrict__ GH,
                                                const float* __restrict__ centers,
                                                const float* __restrict__ b_ih,
                                                float* __restrict__ out) {
  __shared__ __align__(16) char smem[114688];  // 112 KB
  short* sXh = (short*)smem;                   // [64][256] bf16 swz : 32 KB
  short* sXl = (short*)(smem + 32768);         // [64][256] bf16 swz : 32 KB
  char*  sW  = smem + 65536;                   // [96][256] bf16 swz : 48 KB
  float* sC  = (float*)(smem + 65536);         // [64][100] f32 (aliases sW)
  const int t = threadIdx.x;
  const int wid = t >> 6, l = t & 63;
  const int lr = l & 15, lk = l >> 4;
  const int wm = wid >> 1, wn = wid & 1;
  const int b = blockIdx.x;

  // stage X panel: rows b*64 .. b*64+63, straight 32 KB copies (pre-swizzled)
#pragma unroll
  for (int i = 0; i < 8; ++i) {
    int flat = t + 256 * i;
    size_t so = ((size_t)b * 64 + (flat >> 5)) * 512 + (size_t)(flat & 31) * 16;
    int db = (wid * 64 + 256 * i) * 16;
    gload16nt((const char*)Xhi + so, (char*)sXh + db);
    gload16nt((const char*)Xlo + so, (char*)sXl + db);
  }
  __syncthreads();

  for (int nt = 0; nt < 8; ++nt) {
    const int n0 = nt * 96;
    f32x4 acc[2][3];
#pragma unroll
    for (int i = 0; i < 2; ++i)
#pragma unroll
      for (int j = 0; j < 3; ++j) acc[i][j] = (f32x4){0.f, 0.f, 0.f, 0.f};

#pragma unroll
    for (int wp = 0; wp < 2; ++wp) {
      const unsigned short* Ws = wp ? Wpl : Wph;
      // stage W tile 96 x 512B
#pragma unroll
      for (int i = 0; i < 12; ++i) {
        int flat = t + 256 * i;
        size_t so = (size_t)(n0 + (flat >> 5)) * 512 + (size_t)(flat & 31) * 16;
        int db = (wid * 64 + 256 * i) * 16;
        gload16((const char*)Ws + so, sW + db);
      }
      __syncthreads();  // full drain: W visible
      const int np = wp ? 1 : 2;  // Wh: Xh,Xl passes; Wl: Xh pass
      for (int xp = 0; xp < np; ++xp) {
        const short* Xs = xp ? sXl : sXh;
#pragma unroll
        for (int kc = 0; kc < 8; ++kc) {
          const int q = kc * 4 + lk;
          const int seg = (q >> 3) << 7, jj = q & 7;
          short8 af[2];
#pragma unroll
          for (int mi = 0; mi < 2; ++mi) {
            int rl = wm * 32 + mi * 16 + lr;
            af[mi] = *(const short8*)((const char*)Xs + rl * 512 + seg + ((jj ^ (rl & 7)) << 4));
          }
#pragma unroll
          for (int ni = 0; ni < 3; ++ni) {
            int rw = wn * 48 + ni * 16 + lr;
            short8 bf = *(const short8*)(sW + rw * 512 + seg + ((jj ^ (rw & 7)) << 4));
#pragma unroll
            for (int mi = 0; mi < 2; ++mi)
              acc[mi][ni] = __builtin_amdgcn_mfma_f32_16x16x32_bf16(af[mi], bf, acc[mi][ni], 0, 0, 0);
          }
        }
      }
      __syncthreads();  // all sW reads done before restage / sC alias write
    }
    // acc -> sC (rows = slot s, cols = 3*hl + gate)
#pragma unroll
    for (int mi = 0; mi < 2; ++mi)
#pragma unroll
      for (int ni = 0; ni < 3; ++ni)
#pragma unroll
        for (int p = 0; p < 4; ++p) {
          int row = wm * 32 + mi * 16 + lk * 4 + p;
          int col = wn * 48 + ni * 16 + lr;
          sC[row * 100 + col] = acc[mi][ni][p];
        }
    __syncthreads();
    // fused GRU + level-mean: 16 o x 32 h = 512 items, 2 per thread
#pragma unroll
    for (int ii = 0; ii < 2; ++ii) {
      int item = t + 256 * ii;
      int hl = item & 31, o = item >> 5;
      int h = nt * 32 + hl;
      float hprev = centers[o * 256 + h];
      float bir = b_ih[h], biz = b_ih[256 + h], bin = b_ih[512 + h];
      float sum = 0.f;
#pragma unroll
      for (int j = 0; j < 4; ++j) {
        int s = 4 * o + j;
        float gir = sC[s * 100 + 3 * hl + 0] + bir;
        float giz = sC[s * 100 + 3 * hl + 1] + biz;
        float gin = sC[s * 100 + 3 * hl + 2] + bin;
        float rg = sigmf(gir + GH[s * 768 + h]);
        float zg = sigmf(giz + GH[s * 768 + 256 + h]);
        float ng = tanhf2(gin + rg * GH[s * 768 + 512 + h]);
        sum += (1.f - zg) * ng + zg * hprev;
      }
      out[(size_t)o * 65536 + (size_t)b * 256 + h] = 0.25f * sum;
    }
    __syncthreads();  // sC reads done before next ntile's sW stage (alias)
  }
}

// ---------------------------------------------------------------------------
extern "C" void kernel_launch(void* const* d_in, const int* in_sizes, int n_in,
                              void* d_out, int out_size, void* d_ws, size_t ws_size,
                              hipStream_t stream) {
  (void)in_sizes; (void)n_in; (void)out_size; (void)ws_size;
  const float* attn    = (const float*)d_in[0];  // [256][64][4096]
  const float* centers = (const float*)d_in[1];  // [4096][256]
  const float* w_ih    = (const float*)d_in[2];  // [768][256]
  const float* w_hh    = (const float*)d_in[3];  // [768][256]
  const float* b_ih    = (const float*)d_in[4];  // [768]
  const float* b_hh    = (const float*)d_in[5];  // [768]

  char* ws = (char*)d_ws;
  unsigned short* Cth = (unsigned short*)(ws + WS_CTH);
  unsigned short* Ctl = (unsigned short*)(ws + WS_CTL);
  unsigned short* Wph = (unsigned short*)(ws + WS_WPH);
  unsigned short* Wpl = (unsigned short*)(ws + WS_WPL);
  float*          GHp = (float*)(ws + WS_GH);
  float*          csp = (float*)(ws + WS_CSP);
  float*          cs  = (float*)(ws + WS_CS);
  unsigned short* Xhi = (unsigned short*)(ws + WS_XHI);
  unsigned short* Xlo = (unsigned short*)(ws + WS_XLO);
  float* out = (float*)d_out;

  hipLaunchKernelGGL(k_transC, dim3(64, 4), dim3(256), 0, stream, centers, Cth, Ctl);
  hipLaunchKernelGGL(k_csum, dim3(16), dim3(256), 0, stream, centers, csp);
  hipLaunchKernelGGL(k_csum2, dim3(1), dim3(256), 0, stream, csp, cs);
  hipLaunchKernelGGL(k_prepWp, dim3(96), dim3(256), 0, stream, w_ih, Wph, Wpl);
  hipLaunchKernelGGL(k_gh, dim3(64), dim3(256), 0, stream, centers, w_hh, b_hh, GHp);
  hipLaunchKernelGGL(k_stage1, dim3(256), dim3(256), 0, stream, attn, Cth, Ctl, cs, Xhi, Xlo);
  hipLaunchKernelGGL(k_stage2, dim3(256), dim3(256), 0, stream, Xhi, Xlo, Wph, Wpl, GHp, centers, b_ih, out);
}

// Round 9
// 179.839 us; speedup vs baseline: 1.3726x; 1.3726x over previous
//
#include <hip/hip_runtime.h>
#include <stdint.h>

// ---------------------------------------------------------------------------
// MultiScaleGRU fused pipeline (MI355X / gfx950)
//
//   gi = (A @ C) @ w_ih^T + b_ih      A: [16384,4096] fp32 (attention_weights)
//   gh = h @ w_hh^T + b_hh            h: repeat(C[:16], 4)  -> [64,256]
//   r,z = sigmoid(gi_rz + gh_rz); n = tanh(gi_n + r*gh_n)
//   h_new = (1-z)*n + z*h ; out[o,b,:] = mean_j h_new[b, 4o+j, :]
//
// R9: switch bf16+hi/lo-splits -> SINGLE fp16 (11-bit mantissa = 8x lower
// quant error; sigma_gi ~0.009 -> absmax ~0.018, same as the passing bf16-split
// version). Ct shrinks to 2MB (L2-resident even under block drift -> kills the
// L3 delivery bound measured in R8: 1.25GB @ 7.3TB/s = 171us), stage1 B volume
// and MFMA count halve, X is a single 8MB fp16 buffer, stage2 is one pass.
// X stored WITHOUT the A-centering correction; exact fp32 csW[n]=sum_h
// cs[h]*w_ih[n,h] folded into stage-2 bias instead.
// Stage1: BM=32, grid 512, LDS 68KB -> 2 blocks/CU (8 waves/CU of TLP vs
// R8's 4). Same swizzles (16B chunk j ^= row&7 per 128B segment), same
// 2-phase dbuf pipeline.
// ---------------------------------------------------------------------------

typedef _Float16 half8 __attribute__((ext_vector_type(8)));
typedef float f32x4 __attribute__((ext_vector_type(4)));

// workspace layout (bytes)
#define WS_CT   0u          // Ct  : fp16 [256][4096] swz   (2 MB)
#define WS_WP   2097152u    // Wp  : fp16 [768][256]  swz   (384 KB)
#define WS_GH   2490368u    // GH  : f32  [64][768]         (192 KB)
#define WS_CSP  2686976u    // csum partials: f32 [16][256] (16 KB)
#define WS_CS   2703360u    // cs  : f32 [256]              (1 KB)
#define WS_CSW  2704384u    // csW : f32 [768]              (3 KB)
#define WS_X    2707456u    // X   : fp16 [16384][256] swz  (8 MB)
// total 11,096,064 bytes

static __device__ __forceinline__ _Float16 f2h(float x) {
  return (_Float16)x;  // v_cvt_f16_f32, RNE
}
static __device__ __forceinline__ void gload16(const void* g, void* lds) {
  // async global->LDS, 16B/lane; LDS dest = wave-uniform base + lane*16
  __builtin_amdgcn_global_load_lds(
      (const __attribute__((address_space(1))) unsigned int*)g,
      (__attribute__((address_space(3))) unsigned int*)lds, 16, 0, 0);
}
static __device__ __forceinline__ float sigmf(float x) {
  float e = __expf(-fabsf(x));
  float p = 1.f / (1.f + e);
  return x >= 0.f ? p : 1.f - p;
}
static __device__ __forceinline__ float tanhf2(float x) {
  float e = __expf(-2.f * fabsf(x));
  float t = 1.f - 2.f * e / (1.f + e);
  return x >= 0.f ? t : -t;
}

// ---------------------------------------------------------------------------
// prep 1: C[4096][256] f32 -> Ct[256(h)][4096(f)] fp16, swizzled
__global__ void __launch_bounds__(256) k_transC(const float* __restrict__ C,
                                                _Float16* __restrict__ Ct) {
  __shared__ float sT[64][65];
  const int f0 = blockIdx.x * 64, h0 = blockIdx.y * 64;
  const int t = threadIdx.x;
#pragma unroll
  for (int i = 0; i < 4; ++i) {
    int fl = t + 256 * i;
    int r = fl >> 4, c4 = fl & 15;
    float4 v = *(const float4*)(C + (size_t)(f0 + r) * 256 + h0 + c4 * 4);
    sT[r][c4 * 4 + 0] = v.x; sT[r][c4 * 4 + 1] = v.y;
    sT[r][c4 * 4 + 2] = v.z; sT[r][c4 * 4 + 3] = v.w;
  }
  __syncthreads();
#pragma unroll
  for (int i = 0; i < 2; ++i) {
    int q = t + 256 * i;         // 512 chunks of 8 fp16
    int hr = q >> 3, j = q & 7;  // out row (h), f-chunk within 64
    int h = h0 + hr;
    union { half8 v; _Float16 u[8]; } pk;
#pragma unroll
    for (int u = 0; u < 8; ++u) pk.u[u] = f2h(sT[j * 8 + u][hr]);
    size_t off = (size_t)h * 8192 + (size_t)f0 * 2 + (size_t)((j ^ (h & 7)) << 4);
    *(half8*)((char*)Ct + off) = pk.v;
  }
}

// prep 1b: colsum (deterministic 2-step tree) -> cs[h] = 0.5*sum_f C[f][h]
__global__ void __launch_bounds__(256) k_csum(const float* __restrict__ C,
                                              float* __restrict__ part) {
  const int b = blockIdx.x, t = threadIdx.x;
  float s = 0.f;
  for (int k = 0; k < 256; ++k) s += C[(size_t)(b * 256 + k) * 256 + t];
  part[b * 256 + t] = s;
}
__global__ void __launch_bounds__(256) k_csum2(const float* __restrict__ part,
                                               float* __restrict__ csum) {
  const int t = threadIdx.x;
  float s = 0.f;
#pragma unroll
  for (int b = 0; b < 16; ++b) s += part[b * 256 + t];
  csum[t] = 0.5f * s;
}
// prep 1c: csW[n] = sum_h cs[h]*w_ih[n][h]  (exact fp32 bias correction)
__global__ void __launch_bounds__(256) k_csumW(const float* __restrict__ w_ih,
                                               const float* __restrict__ cs,
                                               float* __restrict__ csW) {
  const int n = blockIdx.x * 256 + threadIdx.x;  // 0..767
  float s = 0.f;
  for (int h = 0; h < 256; ++h) s += cs[h] * w_ih[(size_t)n * 256 + h];
  csW[n] = s;
}

// prep 2: w_ih[768][256] f32 -> Wp[n'=3h+g][256] fp16, swizzled
__global__ void __launch_bounds__(256) k_prepWp(const float* __restrict__ w_ih,
                                                _Float16* __restrict__ Wp) {
  int q = blockIdx.x * 256 + threadIdx.x;  // 24576 chunks
  int row = q >> 5, c = q & 31;
  int seg = c >> 3, j = c & 7;
  int srow = (row % 3) * 256 + row / 3;    // gate-interleave permutation
  const float* src = w_ih + (size_t)srow * 256 + c * 8;
  union { half8 v; _Float16 u[8]; } pk;
#pragma unroll
  for (int u = 0; u < 8; ++u) pk.u[u] = f2h(src[u]);
  size_t off = (size_t)row * 512 + seg * 128 + ((j ^ (row & 7)) << 4);
  *(half8*)((char*)Wp + off) = pk.v;
}

// prep 3: GH[64][768] = h @ w_hh^T + b_hh   (exact fp32)
__global__ void __launch_bounds__(256) k_gh(const float* __restrict__ centers,
                                            const float* __restrict__ w_hh,
                                            const float* __restrict__ b_hh,
                                            float* __restrict__ GH) {
  __shared__ __align__(16) float sH[256];
  const int s = blockIdx.x, t = threadIdx.x;
  sH[t] = centers[(size_t)(s >> 2) * 256 + t];
  __syncthreads();
#pragma unroll
  for (int e = 0; e < 3; ++e) {
    int n = e * 256 + t;
    float accv = b_hh[n];
    const float4* w = (const float4*)(w_hh + (size_t)n * 256);
#pragma unroll 8
    for (int k = 0; k < 64; ++k) {
      float4 v = w[k];
      float4 hh = *(const float4*)&sH[k * 4];
      accv += v.x * hh.x + v.y * hh.y + v.z * hh.z + v.w * hh.w;
    }
    GH[(size_t)s * 768 + n] = accv;
  }
}

// ---------------------------------------------------------------------------
// stage 1: X = (A-0.5) @ C   (fp16 MFMA, fp32 accum; colsum folded into
// stage-2 bias). BM=32, BN=256, BK=64. grid 512, 256 thr (4 waves 1Mx4N),
// LDS 68KB -> 2 blocks/CU. 2-phase dbuf B pipeline via global_load_lds;
// A NT reg-staged -> fp16 cvt -> swizzled ds_write.
__global__ void __launch_bounds__(256) k_stage1(const float* __restrict__ A,
                                                const _Float16* __restrict__ Ct,
                                                _Float16* __restrict__ X) {
  __shared__ __align__(16) _Float16 sA[32 * 64];      //  4 KB
  __shared__ __align__(16) _Float16 sB[2][256 * 64];  // 64 KB (dbuf)
  const int t = threadIdx.x;
  const int wid = t >> 6, l = t & 63;
  const int lr = l & 15, lk = l >> 4;
  const int m0 = blockIdx.x * 32;

  f32x4 acc[2][4];
#pragma unroll
  for (int i = 0; i < 2; ++i)
#pragma unroll
    for (int j = 0; j < 4; ++j) acc[i][j] = (f32x4){0.f, 0.f, 0.f, 0.f};

  // A staging: thread t -> row ar (0..31), 8-float chunk aj (0..7)
  const int ar = t >> 3, aj = t & 7;
  const float* aptr = A + (size_t)(m0 + ar) * 4096 + aj * 8;
  const int saw = ar * 128 + ((aj ^ (ar & 7)) << 4);

  // B staging: flat = t + 256*i -> row br+32i, chunk bj; dest linear chunk
  const int br = t >> 3, bj = t & 7;

  // prologue: A(0) regs (NT) + B(0) -> buf 0
  f32x4 a0 = __builtin_nontemporal_load((const f32x4*)(aptr));
  f32x4 a1 = __builtin_nontemporal_load((const f32x4*)(aptr + 4));
#pragma unroll
  for (int i = 0; i < 8; ++i) {
    gload16(Ct + (size_t)(br + 32 * i) * 4096 + bj * 8,
            (char*)&sB[0][0] + (wid * 64 + 256 * i) * 16);
  }
  asm volatile("s_waitcnt vmcnt(0)" ::: "memory");

#pragma unroll 2
  for (int kk = 0; kk < 64; ++kk) {
    const int cur = kk & 1;
    // ds_write A(kk) (centered, RNE cvt) -> sA
    {
      union { half8 v; _Float16 u[8]; } pk;
      pk.u[0] = f2h(a0.x - 0.5f); pk.u[1] = f2h(a0.y - 0.5f);
      pk.u[2] = f2h(a0.z - 0.5f); pk.u[3] = f2h(a0.w - 0.5f);
      pk.u[4] = f2h(a1.x - 0.5f); pk.u[5] = f2h(a1.y - 0.5f);
      pk.u[6] = f2h(a1.z - 0.5f); pk.u[7] = f2h(a1.w - 0.5f);
      *(half8*)((char*)sA + saw) = pk.v;
    }
    // issue next tile: A(kk+1) -> regs (NT), B(kk+1) -> buf[cur^1]
    f32x4 n0, n1;
    if (kk < 63) {
      const float* ap = aptr + (kk + 1) * 64;
      n0 = __builtin_nontemporal_load((const f32x4*)(ap));
      n1 = __builtin_nontemporal_load((const f32x4*)(ap + 4));
#pragma unroll
      for (int i = 0; i < 8; ++i) {
        gload16(Ct + (size_t)(br + 32 * i) * 4096 + (size_t)(kk + 1) * 64 + bj * 8,
                (char*)&sB[cur ^ 1][0] + (wid * 64 + 256 * i) * 16);
      }
    }
    // raw barrier: A(kk) visible; B(kk) drained by prev iter's __syncthreads.
    // Does NOT drain the in-flight B(kk+1) stage.
    asm volatile("s_waitcnt lgkmcnt(0)" ::: "memory");
    __builtin_amdgcn_s_barrier();
    asm volatile("" ::: "memory");

    const char* pA = (const char*)sA;
    const char* pB = (const char*)&sB[cur][0];
#pragma unroll
    for (int kc = 0; kc < 2; ++kc) {
      const int q = kc * 4 + lk;
      half8 af[2];
#pragma unroll
      for (int mi = 0; mi < 2; ++mi) {
        int rl = mi * 16 + lr;
        af[mi] = *(const half8*)(pA + rl * 128 + ((q ^ (rl & 7)) << 4));
      }
#pragma unroll
      for (int ni = 0; ni < 4; ++ni) {
        int rb = wid * 64 + ni * 16 + lr;
        half8 bf = *(const half8*)(pB + rb * 128 + ((q ^ (rb & 7)) << 4));
#pragma unroll
        for (int mi = 0; mi < 2; ++mi)
          acc[mi][ni] = __builtin_amdgcn_mfma_f32_16x16x32_f16(af[mi], bf, acc[mi][ni], 0, 0, 0);
      }
    }
    // drain next-tile stage (vmcnt(0)) + cross-wave reads-done fence
    __syncthreads();
    if (kk < 63) { a0 = n0; a1 = n1; }
  }

  // epilogue: X -> fp16 (RNE), pre-swizzled storage
#pragma unroll
  for (int mi = 0; mi < 2; ++mi)
#pragma unroll
    for (int ni = 0; ni < 4; ++ni)
#pragma unroll
      for (int p = 0; p < 4; ++p) {
        int m = m0 + mi * 16 + lk * 4 + p;        // C/D: row=(lane>>4)*4+reg
        int col = wid * 64 + ni * 16 + lr;        //      col=lane&15
        size_t off = (size_t)m * 512 + ((col >> 6) << 7) +
                     ((((col >> 3) & 7) ^ (m & 7)) << 4) + ((col & 7) << 1);
        *(_Float16*)((char*)X + off) = f2h(acc[mi][ni][p]);
      }
}

// ---------------------------------------------------------------------------
// stage 2: GI = X@W (single fp16 pass) + (b_ih + csW) + fused GRU + mean.
// grid 256 (block = batch b), 256 thr, 4 waves 2Mx2N. X panel (32 KB)
// resident in LDS; W tiles (96x256 fp16, 48 KB) staged once per ntile.
// sC (epilogue) aliases the W buffer.
__global__ void __launch_bounds__(256) k_stage2(const _Float16* __restrict__ X,
                                                const _Float16* __restrict__ Wp,
                                                const float* __restrict__ GH,
                                                const float* __restrict__ centers,
                                                const float* __restrict__ b_ih,
                                                const float* __restrict__ csW,
                                                float* __restrict__ out) {
  __shared__ __align__(16) char smem[81920];   // 80 KB
  _Float16* sX = (_Float16*)smem;              // [64][256] fp16 swz : 32 KB
  char*     sW = smem + 32768;                 // [96][256] fp16 swz : 48 KB
  float*    sC = (float*)(smem + 32768);       // [64][100] f32 (aliases sW)
  const int t = threadIdx.x;
  const int wid = t >> 6, l = t & 63;
  const int lr = l & 15, lk = l >> 4;
  const int wm = wid >> 1, wn = wid & 1;
  const int b = blockIdx.x;

  // stage X panel: rows b*64 .. b*64+63 (raw 16B chunks, layout preserved)
#pragma unroll
  for (int i = 0; i < 8; ++i) {
    int flat = t + 256 * i;
    gload16((const char*)X + ((size_t)b * 64 + (flat >> 5)) * 512 +
                (size_t)(flat & 31) * 16,
            (char*)sX + (wid * 64 + 256 * i) * 16);
  }
  __syncthreads();

  for (int nt = 0; nt < 8; ++nt) {
    const int n0 = nt * 96;
    f32x4 acc[2][3];
#pragma unroll
    for (int i = 0; i < 2; ++i)
#pragma unroll
      for (int j = 0; j < 3; ++j) acc[i][j] = (f32x4){0.f, 0.f, 0.f, 0.f};

    // stage W tile 96 x 512B
#pragma unroll
    for (int i = 0; i < 12; ++i) {
      int flat = t + 256 * i;
      gload16((const char*)Wp + (size_t)(n0 + (flat >> 5)) * 512 +
                  (size_t)(flat & 31) * 16,
              sW + (wid * 64 + 256 * i) * 16);
    }
    __syncthreads();  // full drain: W visible
#pragma unroll
    for (int kc = 0; kc < 8; ++kc) {
      const int q = kc * 4 + lk;
      const int seg = (q >> 3) << 7, jj = q & 7;
      half8 af[2];
#pragma unroll
      for (int mi = 0; mi < 2; ++mi) {
        int rl = wm * 32 + mi * 16 + lr;
        af[mi] = *(const half8*)((const char*)sX + rl * 512 + seg + ((jj ^ (rl & 7)) << 4));
      }
#pragma unroll
      for (int ni = 0; ni < 3; ++ni) {
        int rw = wn * 48 + ni * 16 + lr;
        half8 bf = *(const half8*)(sW + rw * 512 + seg + ((jj ^ (rw & 7)) << 4));
#pragma unroll
        for (int mi = 0; mi < 2; ++mi)
          acc[mi][ni] = __builtin_amdgcn_mfma_f32_16x16x32_f16(af[mi], bf, acc[mi][ni], 0, 0, 0);
      }
    }
    __syncthreads();  // all sW reads done before sC alias write
    // acc -> sC (rows = slot s, cols = 3*hl + gate)
#pragma unroll
    for (int mi = 0; mi < 2; ++mi)
#pragma unroll
      for (int ni = 0; ni < 3; ++ni)
#pragma unroll
        for (int p = 0; p < 4; ++p) {
          int row = wm * 32 + mi * 16 + lk * 4 + p;
          int col = wn * 48 + ni * 16 + lr;
          sC[row * 100 + col] = acc[mi][ni][p];
        }
    __syncthreads();
    // fused GRU + level-mean: 16 o x 32 h = 512 items, 2 per thread
#pragma unroll
    for (int ii = 0; ii < 2; ++ii) {
      int item = t + 256 * ii;
      int hl = item & 31, o = item >> 5;
      int h = nt * 32 + hl;
      float hprev = centers[o * 256 + h];
      float bir = b_ih[h] + csW[h];
      float biz = b_ih[256 + h] + csW[256 + h];
      float bin = b_ih[512 + h] + csW[512 + h];
      float sum = 0.f;
#pragma unroll
      for (int j = 0; j < 4; ++j) {
        int s = 4 * o + j;
        float gir = sC[s * 100 + 3 * hl + 0] + bir;
        float giz = sC[s * 100 + 3 * hl + 1] + biz;
        float gin = sC[s * 100 + 3 * hl + 2] + bin;
        float rg = sigmf(gir + GH[s * 768 + h]);
        float zg = sigmf(giz + GH[s * 768 + 256 + h]);
        float ng = tanhf2(gin + rg * GH[s * 768 + 512 + h]);
        sum += (1.f - zg) * ng + zg * hprev;
      }
      out[(size_t)o * 65536 + (size_t)b * 256 + h] = 0.25f * sum;
    }
    __syncthreads();  // sC reads done before next ntile's sW stage (alias)
  }
}

// ---------------------------------------------------------------------------
extern "C" void kernel_launch(void* const* d_in, const int* in_sizes, int n_in,
                              void* d_out, int out_size, void* d_ws, size_t ws_size,
                              hipStream_t stream) {
  (void)in_sizes; (void)n_in; (void)out_size; (void)ws_size;
  const float* attn    = (const float*)d_in[0];  // [256][64][4096]
  const float* centers = (const float*)d_in[1];  // [4096][256]
  const float* w_ih    = (const float*)d_in[2];  // [768][256]
  const float* w_hh    = (const float*)d_in[3];  // [768][256]
  const float* b_ih    = (const float*)d_in[4];  // [768]
  const float* b_hh    = (const float*)d_in[5];  // [768]

  char* ws = (char*)d_ws;
  _Float16* Ct  = (_Float16*)(ws + WS_CT);
  _Float16* Wpp = (_Float16*)(ws + WS_WP);
  float*    GHp = (float*)(ws + WS_GH);
  float*    csp = (float*)(ws + WS_CSP);
  float*    cs  = (float*)(ws + WS_CS);
  float*    csW = (float*)(ws + WS_CSW);
  _Float16* X   = (_Float16*)(ws + WS_X);
  float* out = (float*)d_out;

  hipLaunchKernelGGL(k_transC, dim3(64, 4), dim3(256), 0, stream, centers, Ct);
  hipLaunchKernelGGL(k_csum, dim3(16), dim3(256), 0, stream, centers, csp);
  hipLaunchKernelGGL(k_csum2, dim3(1), dim3(256), 0, stream, csp, cs);
  hipLaunchKernelGGL(k_csumW, dim3(3), dim3(256), 0, stream, w_ih, cs, csW);
  hipLaunchKernelGGL(k_prepWp, dim3(96), dim3(256), 0, stream, w_ih, Wpp);
  hipLaunchKernelGGL(k_gh, dim3(64), dim3(256), 0, stream, centers, w_hh, b_hh, GHp);
  hipLaunchKernelGGL(k_stage1, dim3(512), dim3(256), 0, stream, attn, Ct, X);
  hipLaunchKernelGGL(k_stage2, dim3(256), dim3(256), 0, stream, X, Wpp, GHp, centers, b_ih, csW, out);
}